// Round 1
// baseline (326.180 us; speedup 1.0000x reference)
//
#include <hip/hip_runtime.h>
#include <math.h>

// StructureLoss: weighted BCE + weighted IoU with 31x31 box-avg spatial weight.
// B=32, C=1, H=W=512, fp32 in, scalar fp32 out.
//
// Single fused kernel: per 64x64 output tile, stage 94x94 target halo in LDS,
// separable sliding-window box sum (vertical then horizontal in-place),
// fused elementwise BCE/sigmoid/weit, wave reduction, atomics into d_ws.
// Finalize kernel combines the 4 per-image sums into the scalar loss.

#define IMG_H 512
#define IMG_W 512
#define NB    32
#define TILE  64
#define HALO  15
#define HSZ   94   // TILE + 2*HALO
#define THS   96   // t-halo LDS row stride (even is fine: column-direction pass)
#define VSS   97   // vertical-sum LDS row stride (odd -> conflict-free row pass)

__device__ __forceinline__ float wave_reduce(float v) {
#pragma unroll
  for (int off = 32; off > 0; off >>= 1) v += __shfl_down(v, off, 64);
  return v;
}

__global__ __launch_bounds__(256) void structure_loss_main(
    const float* __restrict__ x, const float* __restrict__ t,
    float* __restrict__ acc) {
  __shared__ float th[HSZ * THS];   // 94*96*4 = 36096 B
  __shared__ float vs[TILE * VSS];  // 64*97*4 = 24832 B  (total 60928 B)

  const int tid = threadIdx.x;
  const int b  = blockIdx.z;
  const int h0 = blockIdx.y * TILE;
  const int w0 = blockIdx.x * TILE;
  const float* tb = t + (size_t)b * (IMG_H * IMG_W);
  const float* xb = x + (size_t)b * (IMG_H * IMG_W);

  // ---- Stage 1: load 94x94 target halo (zero-padded at image edges) ----
  for (int i = tid; i < HSZ * HSZ; i += 256) {
    int r = i / HSZ;
    int c = i - r * HSZ;
    int gh = h0 - HALO + r;
    int gw = w0 - HALO + c;
    float v = 0.0f;
    if ((unsigned)gh < IMG_H && (unsigned)gw < IMG_W) v = tb[gh * IMG_W + gw];
    th[r * THS + c] = v;
  }
  __syncthreads();

  // ---- Stage 2: vertical 31-row sliding sums -> vs[oh][c], oh:0..63 c:0..93 ----
  if (tid < 188) {
    int c   = tid % 94;
    int oh0 = (tid / 94) * 32;
    float sum = 0.0f;
#pragma unroll
    for (int r = 0; r < 30; ++r) sum += th[(oh0 + r) * THS + c];
#pragma unroll 4
    for (int i = 0; i < 32; ++i) {
      int oh = oh0 + i;
      sum += th[(oh + 30) * THS + c];   // window rows oh..oh+30 (31 rows)
      vs[oh * VSS + c] = sum;
      sum -= th[oh * THS + c];
    }
  }
  __syncthreads();

  // ---- Stage 3: horizontal 31-col sliding sums, box written in-place ----
  // One thread owns an entire row: write pointer trails the additive read
  // pointer by 30 columns, so in-place overwrite is race-free.
  if (tid < 64) {
    float* row = &vs[tid * VSS];
    float sum = 0.0f;
#pragma unroll
    for (int c = 0; c < 30; ++c) sum += row[c];
#pragma unroll 4
    for (int ow = 0; ow < 64; ++ow) {
      sum += row[ow + 30];              // window cols ow..ow+30
      float box = sum;
      sum -= row[ow];                   // read original before overwrite
      row[ow] = box;
    }
  }
  __syncthreads();

  // ---- Stage 4: fused elementwise + per-image accumulation ----
  const float inv_area = 1.0f / 961.0f;
  float aW = 0.f, aWB = 0.f, aI = 0.f, aU = 0.f;
#pragma unroll
  for (int k = 0; k < 16; ++k) {
    int e  = k * 256 + tid;
    int oh = e >> 6;
    int ow = e & 63;
    float box = vs[oh * VSS + ow];
    float tc  = th[(oh + HALO) * THS + (ow + HALO)];
    float xv  = xb[(h0 + oh) * IMG_W + (w0 + ow)];   // coalesced: lanes span ow
    float weit = fmaf(5.0f, fabsf(box * inv_area - tc), 1.0f);
    float bce  = fmaxf(xv, 0.0f) - xv * tc + log1pf(expf(-fabsf(xv)));
    float p    = 1.0f / (1.0f + expf(-xv));
    aW  += weit;
    aWB += weit * bce;
    aI  += p * tc * weit;
    aU  += (p + tc) * weit;
  }

  aW  = wave_reduce(aW);
  aWB = wave_reduce(aWB);
  aI  = wave_reduce(aI);
  aU  = wave_reduce(aU);
  if ((tid & 63) == 0) {
    float* a = acc + b * 4;
    atomicAdd(a + 0, aW);
    atomicAdd(a + 1, aWB);
    atomicAdd(a + 2, aI);
    atomicAdd(a + 3, aU);
  }
}

__global__ void structure_loss_final(const float* __restrict__ acc,
                                     float* __restrict__ out) {
  int b = threadIdx.x;
  float loss = 0.0f;
  if (b < NB) {
    float aW  = acc[b * 4 + 0];
    float aWB = acc[b * 4 + 1];
    float aI  = acc[b * 4 + 2];
    float aU  = acc[b * 4 + 3];
    float wbce = aWB / aW;
    float wiou = 1.0f - (aI + 1.0f) / (aU - aI + 1.0f);
    loss = wbce + wiou;
  }
  loss = wave_reduce(loss);
  if (threadIdx.x == 0) out[0] = loss * (1.0f / (float)NB);
}

extern "C" void kernel_launch(void* const* d_in, const int* in_sizes, int n_in,
                              void* d_out, int out_size, void* d_ws, size_t ws_size,
                              hipStream_t stream) {
  const float* x = (const float*)d_in[0];   // input (logits)
  const float* t = (const float*)d_in[1];   // target
  float* acc = (float*)d_ws;                // 32 images x 4 sums

  // d_ws is poisoned 0xAA before every timed call: zero the accumulators.
  hipMemsetAsync(acc, 0, NB * 4 * sizeof(float), stream);

  dim3 grid(IMG_W / TILE, IMG_H / TILE, NB);  // 8 x 8 x 32 = 2048 blocks
  structure_loss_main<<<grid, 256, 0, stream>>>(x, t, acc);
  structure_loss_final<<<1, 64, 0, stream>>>(acc, (float*)d_out);
}

// Round 2
// 140.152 us; speedup vs baseline: 2.3273x; 2.3273x over previous
//
#include <hip/hip_runtime.h>
#include <math.h>

// StructureLoss — separable two-pass redesign.
// R0 post-mortem: fused-tile kernel was latency-bound (0.24 TB/s eff.) on
// serialized LDS sliding chains with 64-188 active threads and 2 blocks/CU.
// R1: kernel A = vertical 31-box sums, register running sums, coalesced,
// no LDS. Kernel B = horizontal 31-box via skewed-LDS row buffer (2/bank,
// conflict-free) + fused BCE/IoU elementwise + reduction. Full occupancy.

#define IMG_H 512
#define IMG_W 512
#define NB    32
#define HW    (IMG_H * IMG_W)

__device__ __forceinline__ float wave_reduce(float v) {
#pragma unroll
  for (int off = 32; off > 0; off >>= 1) v += __shfl_down(v, off, 64);
  return v;
}

// ---------------- Kernel A: vertical 31-row box sums (zero-padded) --------
// job = (image b, 32-row segment, float2 column pair). seg/b are
// block-uniform -> boundary guards compile to scalar branches.
__global__ __launch_bounds__(256) void vbox(const float* __restrict__ t,
                                            float* __restrict__ vs) {
  int job = blockIdx.x * 256 + threadIdx.x;
  int c2  = job & 255;          // 256 float2 column pairs
  int seg = (job >> 8) & 15;    // 16 segments of 32 rows
  int b   = job >> 12;          // 32 images
  const float2* tb = (const float2*)(t + (size_t)b * HW) + c2;
  float2* vb = (float2*)(vs + (size_t)b * HW) + c2;
  int r0 = seg * 32;
  float sx = 0.f, sy = 0.f;
#pragma unroll
  for (int k = -15; k < 15; ++k) {   // warm-up: rows r0-15 .. r0+14
    int r = r0 + k;
    if ((unsigned)r < IMG_H) { float2 v = tb[r * 256]; sx += v.x; sy += v.y; }
  }
#pragma unroll 4
  for (int i = 0; i < 32; ++i) {
    int r = r0 + i;
    int ra = r + 15;
    if (ra < IMG_H) { float2 v = tb[ra * 256]; sx += v.x; sy += v.y; }
    float2 o; o.x = sx; o.y = sy;
    vb[r * 256] = o;
    int rs = r - 15;
    if (rs >= 0) { float2 v = tb[rs * 256]; sx -= v.x; sy -= v.y; }
  }
}

// ------- Kernel B: horizontal 31-box + fused elementwise + reduction ------
// One wave per image row (4 rows/block). Row staged in LDS with skew
// p(c) = c + (c>>5): lane-l window reads (stride 8) land 2 lanes/bank.
__global__ __launch_bounds__(256) void hbox_fused(const float* __restrict__ x,
                                                  const float* __restrict__ t,
                                                  const float* __restrict__ vs,
                                                  float* __restrict__ acc) {
  __shared__ float rowbuf[4][528];   // 512 + 16 skew slack
  __shared__ float part[4][4];
  int tid  = threadIdx.x;
  int wave = tid >> 6, lane = tid & 63;
  int grow = blockIdx.x * 4 + wave;       // global row 0..16383
  int b    = grow >> 9;                   // block-uniform (512 % 4 == 0)
  const float* vrow = vs + (size_t)grow * IMG_W;
  int cbase = lane * 8;

  // stage vertical sums for this row into skewed LDS (float4 stays intact:
  // cbase%32 in {0,8,16,24} so both float4s share one 32-group -> one skew)
  float4 a0 = ((const float4*)vrow)[lane * 2];
  float4 a1 = ((const float4*)vrow)[lane * 2 + 1];
  float* rb = rowbuf[wave];
  int pb = cbase + (cbase >> 5);
  *(float4*)(rb + pb)     = a0;
  *(float4*)(rb + pb + 4) = a1;
  __syncthreads();

  // sliding 31-sum over columns cbase..cbase+7
  float sum = 0.f;
#pragma unroll
  for (int k = -15; k < 15; ++k) {
    int c = cbase + k;
    if ((unsigned)c < IMG_W) sum += rb[c + (c >> 5)];
  }
  float box[8];
#pragma unroll
  for (int j = 0; j < 8; ++j) {
    int ca = cbase + 15 + j;             // always >= 0
    if (ca < IMG_W) sum += rb[ca + (ca >> 5)];
    box[j] = sum;
    int cs = cbase - 15 + j;             // always < IMG_W
    if (cs >= 0) sum -= rb[cs + (cs >> 5)];
  }

  // fused elementwise
  const float* xrow = x + (size_t)grow * IMG_W;
  const float* trow = t + (size_t)grow * IMG_W;
  float4 x0 = ((const float4*)xrow)[lane * 2], x1 = ((const float4*)xrow)[lane * 2 + 1];
  float4 t0 = ((const float4*)trow)[lane * 2], t1 = ((const float4*)trow)[lane * 2 + 1];
  float xv[8] = {x0.x, x0.y, x0.z, x0.w, x1.x, x1.y, x1.z, x1.w};
  float tv[8] = {t0.x, t0.y, t0.z, t0.w, t1.x, t1.y, t1.z, t1.w};
  const float inv_area = 1.0f / 961.0f;
  float aW = 0.f, aWB = 0.f, aI = 0.f, aU = 0.f;
#pragma unroll
  for (int j = 0; j < 8; ++j) {
    float w   = fmaf(5.0f, fabsf(box[j] * inv_area - tv[j]), 1.0f);
    float ez  = __expf(-fabsf(xv[j]));
    float bce = fmaxf(xv[j], 0.f) - xv[j] * tv[j] + __logf(1.0f + ez);
    float p   = 1.0f / (1.0f + __expf(-xv[j]));
    aW  += w;
    aWB += w * bce;
    aI  += p * tv[j] * w;
    aU  += (p + tv[j]) * w;
  }

  aW  = wave_reduce(aW);
  aWB = wave_reduce(aWB);
  aI  = wave_reduce(aI);
  aU  = wave_reduce(aU);
  if (lane == 0) {
    part[wave][0] = aW; part[wave][1] = aWB;
    part[wave][2] = aI; part[wave][3] = aU;
  }
  __syncthreads();
  if (tid < 4) {
    float s = part[0][tid] + part[1][tid] + part[2][tid] + part[3][tid];
    atomicAdd(acc + b * 4 + tid, s);
  }
}

// ---------------- finalize: combine 32x4 sums -> scalar loss --------------
__global__ void structure_loss_final(const float* __restrict__ acc,
                                     float* __restrict__ out) {
  int b = threadIdx.x;
  float loss = 0.0f;
  if (b < NB) {
    float aW  = acc[b * 4 + 0];
    float aWB = acc[b * 4 + 1];
    float aI  = acc[b * 4 + 2];
    float aU  = acc[b * 4 + 3];
    loss = aWB / aW + 1.0f - (aI + 1.0f) / (aU - aI + 1.0f);
  }
  loss = wave_reduce(loss);
  if (threadIdx.x == 0) out[0] = loss * (1.0f / (float)NB);
}

// ---------------- fallback (R0 fused tile) if ws too small ----------------
#define TILE  64
#define HALO  15
#define HSZ   94
#define THS   96
#define VSS   97

__global__ __launch_bounds__(256) void structure_loss_main(
    const float* __restrict__ x, const float* __restrict__ t,
    float* __restrict__ acc) {
  __shared__ float th[HSZ * THS];
  __shared__ float vsh[TILE * VSS];
  const int tid = threadIdx.x;
  const int b  = blockIdx.z;
  const int h0 = blockIdx.y * TILE;
  const int w0 = blockIdx.x * TILE;
  const float* tb = t + (size_t)b * HW;
  const float* xb = x + (size_t)b * HW;
  for (int i = tid; i < HSZ * HSZ; i += 256) {
    int r = i / HSZ, c = i - r * HSZ;
    int gh = h0 - HALO + r, gw = w0 - HALO + c;
    float v = 0.0f;
    if ((unsigned)gh < IMG_H && (unsigned)gw < IMG_W) v = tb[gh * IMG_W + gw];
    th[r * THS + c] = v;
  }
  __syncthreads();
  if (tid < 188) {
    int c = tid % 94, oh0 = (tid / 94) * 32;
    float sum = 0.0f;
#pragma unroll
    for (int r = 0; r < 30; ++r) sum += th[(oh0 + r) * THS + c];
#pragma unroll 4
    for (int i = 0; i < 32; ++i) {
      int oh = oh0 + i;
      sum += th[(oh + 30) * THS + c];
      vsh[oh * VSS + c] = sum;
      sum -= th[oh * THS + c];
    }
  }
  __syncthreads();
  if (tid < 64) {
    float* row = &vsh[tid * VSS];
    float sum = 0.0f;
#pragma unroll
    for (int c = 0; c < 30; ++c) sum += row[c];
#pragma unroll 4
    for (int ow = 0; ow < 64; ++ow) {
      sum += row[ow + 30];
      float bx = sum;
      sum -= row[ow];
      row[ow] = bx;
    }
  }
  __syncthreads();
  const float inv_area = 1.0f / 961.0f;
  float aW = 0.f, aWB = 0.f, aI = 0.f, aU = 0.f;
#pragma unroll
  for (int k = 0; k < 16; ++k) {
    int e = k * 256 + tid;
    int oh = e >> 6, ow = e & 63;
    float bx = vsh[oh * VSS + ow];
    float tc = th[(oh + HALO) * THS + (ow + HALO)];
    float xv = xb[(h0 + oh) * IMG_W + (w0 + ow)];
    float w  = fmaf(5.0f, fabsf(bx * inv_area - tc), 1.0f);
    float bce = fmaxf(xv, 0.0f) - xv * tc + log1pf(expf(-fabsf(xv)));
    float p = 1.0f / (1.0f + expf(-xv));
    aW += w; aWB += w * bce; aI += p * tc * w; aU += (p + tc) * w;
  }
  aW = wave_reduce(aW); aWB = wave_reduce(aWB);
  aI = wave_reduce(aI); aU = wave_reduce(aU);
  if ((tid & 63) == 0) {
    float* a = acc + b * 4;
    atomicAdd(a + 0, aW); atomicAdd(a + 1, aWB);
    atomicAdd(a + 2, aI); atomicAdd(a + 3, aU);
  }
}

extern "C" void kernel_launch(void* const* d_in, const int* in_sizes, int n_in,
                              void* d_out, int out_size, void* d_ws, size_t ws_size,
                              hipStream_t stream) {
  const float* x = (const float*)d_in[0];
  const float* t = (const float*)d_in[1];
  float* acc = (float*)d_ws;                    // 32 x 4 sums (512 B)
  float* vs  = (float*)d_ws + 128;              // 33.5 MB intermediate

  hipMemsetAsync(acc, 0, NB * 4 * sizeof(float), stream);

  size_t need = 512 + (size_t)NB * HW * sizeof(float);
  if (ws_size >= need) {
    vbox<<<512, 256, 0, stream>>>(t, vs);                       // 131072 jobs
    hbox_fused<<<IMG_H * NB / 4, 256, 0, stream>>>(x, t, vs, acc);  // 4096 blocks
  } else {
    dim3 grid(IMG_W / TILE, IMG_H / TILE, NB);
    structure_loss_main<<<grid, 256, 0, stream>>>(x, t, acc);
  }
  structure_loss_final<<<1, 64, 0, stream>>>(acc, (float*)d_out);
}

// Round 3
// 117.143 us; speedup vs baseline: 2.7845x; 1.1964x over previous
//
#include <hip/hip_runtime.h>
#include <math.h>

// StructureLoss — single fused kernel (R2).
// R1 post-mortem: harness d_ws poison (~41 us, 268 MB fill) is inside the
// timed window; our two-pass kernels cost ~90 us with a 67 MB / ~11 us floor.
// R2 removes the 33.5 MB 'vs' round-trip entirely: per block (1 image x 16
// output rows), vertical 31-row running sums in registers -> skewed LDS row
// buffer with zeroed pads (no masks, 2 lanes/bank window reads) -> fused
// horizontal sliding sum + BCE/IoU elementwise -> block partials (no atomics).

#define IMG_H 512
#define IMG_W 512
#define NB    32
#define HW    (IMG_H * IMG_W)
#define RG    16              // output rows per block
#define NGRP  (IMG_H / RG)    // 32 row-groups per image
#define VST   560             // skewed LDS row stride (floats)

// LDS column index: cc in [-15, 526] -> [0, 558]; pads at cc<0 and cc>511
// are pre-zeroed. (cc>>5) skew => stride-32 sub-chunk reads are 2 lanes/bank.
__device__ __forceinline__ int vidx(int cc) { return cc + 16 + (cc >> 5); }

__device__ __forceinline__ float wave_reduce(float v) {
#pragma unroll
  for (int off = 32; off > 0; off >>= 1) v += __shfl_down(v, off, 64);
  return v;
}

__global__ __launch_bounds__(256) void sloss_main(const float* __restrict__ x,
                                                  const float* __restrict__ t,
                                                  float* __restrict__ part) {
  __shared__ float vls[RG * VST];   // 16*560*4 = 35840 B
  __shared__ float red[4][4];

  const int tid = threadIdx.x;
  const int img = blockIdx.x >> 5;
  const int grp = blockIdx.x & 31;
  const int r0  = grp * RG;
  const float* tb = t + (size_t)img * HW;
  const float* xb = x + (size_t)img * HW;

  // zero the 15 left / 15 right pad cells of each LDS row
  if (tid < RG * 30) {
    int r = tid / 30, k = tid % 30;
    vls[r * VST + (k < 15 ? k : 529 + k)] = 0.f;   // right pads: 544..558
  }

  // ---- Stage 1: vertical 31-row running sums (thread owns cols 2t,2t+1) ----
  {
    const float2* tc2 = (const float2*)tb + tid;   // row stride = 256 float2
    const int li = vidx(2 * tid);                  // pair stays contiguous
    float sx = 0.f, sy = 0.f;
    if (grp >= 1 && grp <= 30) {                   // interior: no row guards
#pragma unroll
      for (int k = -15; k < 15; ++k) {
        float2 v = tc2[(r0 + k) * 256]; sx += v.x; sy += v.y;
      }
#pragma unroll 4
      for (int i = 0; i < RG; ++i) {
        float2 v = tc2[(r0 + i + 15) * 256]; sx += v.x; sy += v.y;
        vls[i * VST + li] = sx; vls[i * VST + li + 1] = sy;
        float2 u = tc2[(r0 + i - 15) * 256]; sx -= u.x; sy -= u.y;
      }
    } else {                                       // edge groups: guarded
#pragma unroll
      for (int k = -15; k < 15; ++k) {
        int r = r0 + k;
        if ((unsigned)r < IMG_H) { float2 v = tc2[r * 256]; sx += v.x; sy += v.y; }
      }
#pragma unroll 4
      for (int i = 0; i < RG; ++i) {
        int ra = r0 + i + 15;
        if (ra < IMG_H) { float2 v = tc2[ra * 256]; sx += v.x; sy += v.y; }
        vls[i * VST + li] = sx; vls[i * VST + li + 1] = sy;
        int rs = r0 + i - 15;
        if (rs >= 0) { float2 u = tc2[rs * 256]; sx -= u.x; sy -= u.y; }
      }
    }
  }
  __syncthreads();

  // ---- Stage 2: horizontal sliding 31-sum + fused elementwise ----
  const int row = tid >> 4;                 // 0..15
  const int sub = tid & 15;                 // 0..15 (32-col sub-chunk)
  const int c0  = sub * 32;
  const float* vr = &vls[row * VST];
  const float* xr = xb + (size_t)(r0 + row) * IMG_W;
  const float* tr = tb + (size_t)(r0 + row) * IMG_W;

  float sum = 0.f;
#pragma unroll
  for (int k = -15; k < 15; ++k) sum += vr[vidx(c0 + k)];

  const float inv_area = 1.0f / 961.0f;
  float aW = 0.f, aWB = 0.f, aI = 0.f, aU = 0.f;
#pragma unroll
  for (int jc = 0; jc < 4; ++jc) {
    int cb = c0 + jc * 8;                   // 32 B aligned
    float4 x0 = *(const float4*)(xr + cb);
    float4 x1 = *(const float4*)(xr + cb + 4);
    float4 t0 = *(const float4*)(tr + cb);
    float4 t1 = *(const float4*)(tr + cb + 4);
    float xa[8] = {x0.x, x0.y, x0.z, x0.w, x1.x, x1.y, x1.z, x1.w};
    float ta[8] = {t0.x, t0.y, t0.z, t0.w, t1.x, t1.y, t1.z, t1.w};
#pragma unroll
    for (int j = 0; j < 8; ++j) {
      int cc = cb + j;
      sum += vr[vidx(cc + 15)];
      float box = sum;
      sum -= vr[vidx(cc - 15)];
      float tv = ta[j], xv = xa[j];
      float w   = fmaf(5.0f, fabsf(box * inv_area - tv), 1.0f);
      float ez  = __expf(-fabsf(xv));
      float bce = fmaxf(xv, 0.f) - xv * tv + __logf(1.0f + ez);
      float p   = 1.0f / (1.0f + __expf(-xv));
      aW  += w;
      aWB += w * bce;
      aI  += p * tv * w;
      aU  += (p + tv) * w;
    }
  }

  aW  = wave_reduce(aW);
  aWB = wave_reduce(aWB);
  aI  = wave_reduce(aI);
  aU  = wave_reduce(aU);
  const int wv = tid >> 6, ln = tid & 63;
  if (ln == 0) { red[wv][0] = aW; red[wv][1] = aWB; red[wv][2] = aI; red[wv][3] = aU; }
  __syncthreads();
  if (tid < 4)
    part[blockIdx.x * 4 + tid] =
        red[0][tid] + red[1][tid] + red[2][tid] + red[3][tid];
}

// ---- finalize: reduce 1024 block-partials -> scalar loss ----
__global__ void sloss_final(const float* __restrict__ part,
                            float* __restrict__ out) {
  __shared__ float s[128];
  int tid = threadIdx.x;          // 128 threads
  int img = tid >> 2, q = tid & 3;
  float v = 0.f;
#pragma unroll 4
  for (int g = 0; g < NGRP; ++g) v += part[((img << 5) + g) * 4 + q];
  s[tid] = v;
  __syncthreads();
  float loss = 0.f;
  if (tid < NB) {
    float aW  = s[tid * 4 + 0];
    float aWB = s[tid * 4 + 1];
    float aI  = s[tid * 4 + 2];
    float aU  = s[tid * 4 + 3];
    loss = aWB / aW + 1.0f - (aI + 1.0f) / (aU - aI + 1.0f);
  }
  loss = wave_reduce(loss);
  if (tid == 0) out[0] = loss * (1.0f / (float)NB);
}

extern "C" void kernel_launch(void* const* d_in, const int* in_sizes, int n_in,
                              void* d_out, int out_size, void* d_ws, size_t ws_size,
                              hipStream_t stream) {
  const float* x = (const float*)d_in[0];
  const float* t = (const float*)d_in[1];
  float* part = (float*)d_ws;     // 1024 blocks x 4 floats, fully overwritten

  sloss_main<<<NB * NGRP, 256, 0, stream>>>(x, t, part);
  sloss_final<<<1, 128, 0, stream>>>(part, (float*)d_out);
}